// Round 6
// baseline (154.458 us; speedup 1.0000x reference)
//
#include <hip/hip_runtime.h>
#include <hip/hip_bf16.h>
#include <cstddef>

#define NAGENT 8
#define DIN    128
#define HID    64
#define NACT   16

typedef __attribute__((ext_vector_type(8))) short bf16x8;
typedef __attribute__((ext_vector_type(4))) float f32x4;

__device__ __forceinline__ short f2bf(float f) {
    __hip_bfloat16 h = __float2bfloat16(f);      // RNE; pairs pack to v_cvt_pk_bf16_f32
    union { __hip_bfloat16 h; short s; } u; u.h = h;
    return u.s;
}
__device__ __forceinline__ float sigmoid_f(float v) { return 1.0f / (1.0f + __expf(-v)); }
__device__ __forceinline__ float tanh_f(float v) {
    v = fminf(fmaxf(v, -15.0f), 15.0f);
    float e = __expf(2.0f * v);
    return (e - 1.0f) / (e + 1.0f);
}
__device__ __forceinline__ bf16x8 cvt8pair(float4 v0, float4 v1) {
    bf16x8 r;
    r[0] = f2bf(v0.x); r[1] = f2bf(v0.y); r[2] = f2bf(v0.z); r[3] = f2bf(v0.w);
    r[4] = f2bf(v1.x); r[5] = f2bf(v1.y); r[6] = f2bf(v1.z); r[7] = f2bf(v1.w);
    return r;
}
__device__ __forceinline__ void gload_lds16(const void* g, void* l) {
    __builtin_amdgcn_global_load_lds(
        (const __attribute__((address_space(1))) unsigned int*)g,
        (__attribute__((address_space(3))) unsigned int*)l, 16, 0, 0);
}

// ---------------- weight fp32 -> bf16 fragment-major packing ----------------
// Per-agent packed layout (shorts), base a*33792:
//   W1  chunks c in [0,1024):    c = (n*4+k)*64 + lane      -> W1[a][n*16+lr][k*32+lk*8 ..+8]
//   Wih chunks c in [1024,2560): c-1024 = ((g*4+n)*2+kk)*64+lane -> Wih[a][g*64+n*16+lr][kk*32+lk*8..]
//   Whh chunks c in [2560,4096): same with Whh
//   W2  chunks c in [4096,4224): c-4096 = kk*64+lane        -> W2[a][lr][kk*32+lk*8..]
extern "C" __global__ void __launch_bounds__(256)
conv_weights_packed(const float* __restrict__ W1, const float* __restrict__ Wih,
                    const float* __restrict__ Whh, const float* __restrict__ W2,
                    short* __restrict__ ws)
{
    const int a = blockIdx.y;
    const int c = blockIdx.x * 256 + threadIdx.x;
    if (c >= 4224) return;
    const int lane = c & 63, lr = lane & 15, lk = lane >> 4;
    const float* src;
    if (c < 1024) {
        int n = c >> 8, k = (c >> 6) & 3;
        src = W1 + a * 8192 + (n * 16 + lr) * 128 + k * 32 + lk * 8;
    } else if (c < 2560) {
        int idx = (c - 1024) >> 6;
        int g = idx >> 3, n = (idx >> 1) & 3, kk = idx & 1;
        src = Wih + a * 12288 + (g * 64 + n * 16 + lr) * 64 + kk * 32 + lk * 8;
    } else if (c < 4096) {
        int idx = (c - 2560) >> 6;
        int g = idx >> 3, n = (idx >> 1) & 3, kk = idx & 1;
        src = Whh + a * 12288 + (g * 64 + n * 16 + lr) * 64 + kk * 32 + lk * 8;
    } else {
        int kk = (c - 4096) >> 6;
        src = W2 + a * 1024 + lr * 64 + kk * 32 + lk * 8;
    }
    float4 v0 = ((const float4*)src)[0];
    float4 v1 = ((const float4*)src)[1];
    bf16x8 o = cvt8pair(v0, v1);
    *(bf16x8*)(ws + (size_t)a * 33792 + (size_t)c * 8) = o;
}

// ---------------- main fused kernel ----------------
// grid (B/256, A), 512 threads (8 waves). LDS = 64KB weights + 16KB transpose
// = 81920B exactly -> 2 blocks/CU (160KiB) = 16 waves/CU = 4 waves/SIMD.
// W2 (1KB/agent) is read from L2. No inter-wave sync after the staging barrier.
// No register prefetch arrays (TLP replaces ILP); hp/W2 fragments prefetched
// at tile start; all h-path MFMAs run before the first z1 LDS read.
extern "C" __global__ void __launch_bounds__(512, 4)
rnn_main(const float* __restrict__ x,     // [B*A, D]
         const float* __restrict__ hin,   // [B, A, H]
         const float* __restrict__ b1, const float* __restrict__ bih,
         const float* __restrict__ bhh, const float* __restrict__ b2,
         const short* __restrict__ wsp,   // packed bf16 weights
         float* __restrict__ qout,        // [B*A, NACT]
         float* __restrict__ hout)        // [B, A, H]
{
    const int a    = blockIdx.y;
    const int bx   = blockIdx.x;
    const int t    = threadIdx.x;
    const int wid  = t >> 6;              // 0..7
    const int lane = t & 63;
    const int lr   = lane & 15;
    const int lk   = lane >> 4;

    __shared__ short wlds[32768];           // 64 KB: W1 | Wih | Whh (packed chunks 0..4095)
    __shared__ short zs[8 * 1024];          // 8 per-wave 2KB transpose buffers (16 KB)
    char* zb = (char*)(zs + wid * 1024);

    // ---- stage weights: 64 rounds x 1KB, split across 8 waves ----
    const short* wsA = wsp + (size_t)a * 33792;
    for (int r = wid; r < 64; r += 8)
        gload_lds16(wsA + (size_t)r * 512 + lane * 8, wlds + r * 512);

    // ---- hoist biases (tile-invariant, per-lane) ----
    float b1v[4], biv[12], bhv[12];
    #pragma unroll
    for (int n = 0; n < 4; ++n) b1v[n] = b1[a * HID + n * 16 + lr];
    #pragma unroll
    for (int g = 0; g < 3; ++g)
        #pragma unroll
        for (int n = 0; n < 4; ++n) {
            biv[g * 4 + n] = bih[a * 3 * HID + g * HID + n * 16 + lr];
            bhv[g * 4 + n] = bhh[a * 3 * HID + g * HID + n * 16 + lr];
        }
    float bqv = b2[a * NACT + lr];

    __syncthreads();   // weights staged (drains vmcnt)

    const int tile0 = bx * 16 + wid * 2;

    #pragma unroll
    for (int i = 0; i < 2; ++i) {
        const int tile = tile0 + i;
        const int arow = tile * 16 + lr;
        const float* xrow = x + ((size_t)arow * NAGENT + a) * DIN + lk * 8;
        const float* hrow = hin + ((size_t)arow * NAGENT + a) * HID + lk * 8;

        // ---- issue all global loads for this tile up front ----
        // W2 fragments (L2, consumed at the very end)
        bf16x8 w2f0 = *(const bf16x8*)(wsA + (4096 + 0 * 64 + lane) * 8);
        bf16x8 w2f1 = *(const bf16x8*)(wsA + (4096 + 1 * 64 + lane) * 8);
        // hp: h in D-layout for the GRU blend (consumed late)
        float hp[16];
        #pragma unroll
        for (int n = 0; n < 4; ++n)
            #pragma unroll
            for (int j = 0; j < 4; ++j)
                hp[n * 4 + j] =
                    hin[((size_t)(tile * 16 + lk * 4 + j) * NAGENT + a) * HID + n * 16 + lr];
        // x / h rows -> bf16 fragments
        bf16x8 xf[4], hf[2];
        #pragma unroll
        for (int k = 0; k < 4; ++k)
            xf[k] = cvt8pair(*(const float4*)(xrow + k * 32),
                             *(const float4*)(xrow + k * 32 + 4));
        #pragma unroll
        for (int kk = 0; kk < 2; ++kk)
            hf[kk] = cvt8pair(*(const float4*)(hrow + kk * 32),
                              *(const float4*)(hrow + kk * 32 + 4));

        // ---- fc1: z1 = relu(x @ W1^T + b1) ----
        f32x4 acc1[4];
        #pragma unroll
        for (int n = 0; n < 4; ++n) acc1[n] = (f32x4){b1v[n], b1v[n], b1v[n], b1v[n]};
        #pragma unroll
        for (int k = 0; k < 4; ++k)
            #pragma unroll
            for (int n = 0; n < 4; ++n) {
                bf16x8 wb = *(const bf16x8*)(wlds + ((n * 4 + k) * 64 + lane) * 8);
                acc1[n] = __builtin_amdgcn_mfma_f32_16x16x32_bf16(xf[k], wb, acc1[n], 0, 0, 0);
            }
        #pragma unroll
        for (int n = 0; n < 4; ++n)
            #pragma unroll
            for (int j = 0; j < 4; ++j) {
                int row = lk * 4 + j, col = n * 16 + lr;
                *(short*)(zb + row * 128 + ((col * 2) ^ ((row & 7) << 4))) =
                    f2bf(fmaxf(acc1[n][j], 0.0f));
            }

        // ---- h-path MFMAs for ALL gates first (independent of z1; covers the
        //      z1 LDS write->read round trip) ----
        f32x4 aH[12];
        #pragma unroll
        for (int g = 0; g < 3; ++g)
            #pragma unroll
            for (int n = 0; n < 4; ++n) {
                float bh = bhv[g * 4 + n];
                aH[g * 4 + n] = (f32x4){bh, bh, bh, bh};
            }
        #pragma unroll
        for (int kk = 0; kk < 2; ++kk)
            #pragma unroll
            for (int g = 0; g < 3; ++g)
                #pragma unroll
                for (int n = 0; n < 4; ++n) {
                    bf16x8 wh = *(const bf16x8*)(wlds + 20480 +
                                  (((g * 4 + n) * 2 + kk) * 64 + lane) * 8);
                    aH[g * 4 + n] =
                        __builtin_amdgcn_mfma_f32_16x16x32_bf16(hf[kk], wh, aH[g * 4 + n], 0, 0, 0);
                }

        // ---- z1-path MFMAs ----
        bf16x8 za0 = *(const bf16x8*)(zb + lr * 128 + ((0 * 64 + lk * 16) ^ ((lr & 7) << 4)));
        bf16x8 za1 = *(const bf16x8*)(zb + lr * 128 + ((1 * 64 + lk * 16) ^ ((lr & 7) << 4)));

        float rg[16], zg[16];
        #pragma unroll
        for (int g = 0; g < 3; ++g) {
            f32x4 aI[4];
            #pragma unroll
            for (int n = 0; n < 4; ++n) {
                float bi = biv[g * 4 + n];
                aI[n] = (f32x4){bi, bi, bi, bi};
            }
            #pragma unroll
            for (int n = 0; n < 4; ++n) {
                bf16x8 wi0 = *(const bf16x8*)(wlds + 8192 +
                              (((g * 4 + n) * 2 + 0) * 64 + lane) * 8);
                bf16x8 wi1 = *(const bf16x8*)(wlds + 8192 +
                              (((g * 4 + n) * 2 + 1) * 64 + lane) * 8);
                aI[n] = __builtin_amdgcn_mfma_f32_16x16x32_bf16(za0, wi0, aI[n], 0, 0, 0);
                aI[n] = __builtin_amdgcn_mfma_f32_16x16x32_bf16(za1, wi1, aI[n], 0, 0, 0);
            }
            if (g == 0) {
                #pragma unroll
                for (int n = 0; n < 4; ++n)
                    #pragma unroll
                    for (int j = 0; j < 4; ++j)
                        rg[n * 4 + j] = sigmoid_f(aI[n][j] + aH[n][j]);
            } else if (g == 1) {
                #pragma unroll
                for (int n = 0; n < 4; ++n)
                    #pragma unroll
                    for (int j = 0; j < 4; ++j)
                        zg[n * 4 + j] = sigmoid_f(aI[n][j] + aH[4 + n][j]);
            } else {
                #pragma unroll
                for (int n = 0; n < 4; ++n)
                    #pragma unroll
                    for (int j = 0; j < 4; ++j) {
                        int row = lk * 4 + j, col = n * 16 + lr;
                        float nn = tanh_f(aI[n][j] + rg[n * 4 + j] * aH[8 + n][j]);
                        float zv = zg[n * 4 + j];
                        float hv = (1.0f - zv) * nn + zv * hp[n * 4 + j];
                        hout[((size_t)(tile * 16 + row) * NAGENT + a) * HID + col] = hv;
                        *(short*)(zb + row * 128 + ((col * 2) ^ ((row & 7) << 4))) = f2bf(hv);
                    }
            }
        }

        // ---- fc2: q = h_new @ W2^T + b2 ----
        f32x4 q = (f32x4){bqv, bqv, bqv, bqv};
        bf16x8 ha0 = *(const bf16x8*)(zb + lr * 128 + ((0 * 64 + lk * 16) ^ ((lr & 7) << 4)));
        bf16x8 ha1 = *(const bf16x8*)(zb + lr * 128 + ((1 * 64 + lk * 16) ^ ((lr & 7) << 4)));
        q = __builtin_amdgcn_mfma_f32_16x16x32_bf16(ha0, w2f0, q, 0, 0, 0);
        q = __builtin_amdgcn_mfma_f32_16x16x32_bf16(ha1, w2f1, q, 0, 0, 0);
        #pragma unroll
        for (int j = 0; j < 4; ++j)
            qout[((size_t)(tile * 16 + lk * 4 + j) * NAGENT + a) * NACT + lr] = q[j];
    }
}

extern "C" void kernel_launch(void* const* d_in, const int* in_sizes, int n_in,
                              void* d_out, int out_size, void* d_ws, size_t ws_size,
                              hipStream_t stream)
{
    const float* x   = (const float*)d_in[0];
    const float* hin = (const float*)d_in[1];
    const float* W1  = (const float*)d_in[2];
    const float* b1  = (const float*)d_in[3];
    const float* Wih = (const float*)d_in[4];
    const float* bih = (const float*)d_in[5];
    const float* Whh = (const float*)d_in[6];
    const float* bhh = (const float*)d_in[7];
    const float* W2  = (const float*)d_in[8];
    const float* b2  = (const float*)d_in[9];

    const int B = in_sizes[0] / (NAGENT * DIN);   // 16384

    float* qout = (float*)d_out;                              // [B*A, NACT]
    float* hout = (float*)d_out + (size_t)B * NAGENT * NACT;  // [B, A, H]

    short* wsp = (short*)d_ws;                                // 540,672 B packed

    conv_weights_packed<<<dim3(17, NAGENT), 256, 0, stream>>>(W1, Wih, Whh, W2, wsp);

    dim3 grid(B / 256, NAGENT);
    rnn_main<<<grid, 512, 0, stream>>>(x, hin, b1, bih, bhh, b2, wsp, qout, hout);
}

// Round 7
// 64.192 us; speedup vs baseline: 2.4062x; 2.4062x over previous
//
#include <hip/hip_runtime.h>
#include <hip/hip_bf16.h>
#include <cstddef>

#define NAGENT 8
#define DIN    128
#define HID    64
#define NACT   16

typedef __attribute__((ext_vector_type(8))) short bf16x8;
typedef __attribute__((ext_vector_type(4))) float f32x4;

__device__ __forceinline__ short f2bf(float f) {
    __hip_bfloat16 h = __float2bfloat16(f);      // RNE; pairs pack to v_cvt_pk_bf16_f32
    union { __hip_bfloat16 h; short s; } u; u.h = h;
    return u.s;
}
__device__ __forceinline__ float sigmoid_f(float v) { return 1.0f / (1.0f + __expf(-v)); }
__device__ __forceinline__ float tanh_f(float v) {
    v = fminf(fmaxf(v, -15.0f), 15.0f);
    float e = __expf(2.0f * v);
    return (e - 1.0f) / (e + 1.0f);
}
__device__ __forceinline__ bf16x8 cvt8pair(float4 v0, float4 v1) {
    bf16x8 r;
    r[0] = f2bf(v0.x); r[1] = f2bf(v0.y); r[2] = f2bf(v0.z); r[3] = f2bf(v0.w);
    r[4] = f2bf(v1.x); r[5] = f2bf(v1.y); r[6] = f2bf(v1.z); r[7] = f2bf(v1.w);
    return r;
}
__device__ __forceinline__ void gload_lds16(const void* g, void* l) {
    __builtin_amdgcn_global_load_lds(
        (const __attribute__((address_space(1))) unsigned int*)g,
        (__attribute__((address_space(3))) unsigned int*)l, 16, 0, 0);
}

// ---------------- weight fp32 -> bf16 fragment-major packing ----------------
// Per-agent packed layout (shorts), base a*33792:
//   W1  chunks c in [0,1024):    c = (n*4+k)*64 + lane      -> W1[a][n*16+lr][k*32+lk*8 ..+8]
//   Wih chunks c in [1024,2560): c-1024 = ((g*4+n)*2+kk)*64+lane -> Wih[a][g*64+n*16+lr][kk*32+lk*8..]
//   Whh chunks c in [2560,4096): same with Whh
//   W2  chunks c in [4096,4224): c-4096 = kk*64+lane        -> W2[a][lr][kk*32+lk*8..]
extern "C" __global__ void __launch_bounds__(256)
conv_weights_packed(const float* __restrict__ W1, const float* __restrict__ Wih,
                    const float* __restrict__ Whh, const float* __restrict__ W2,
                    short* __restrict__ ws)
{
    const int a = blockIdx.y;
    const int c = blockIdx.x * 256 + threadIdx.x;
    if (c >= 4224) return;
    const int lane = c & 63, lr = lane & 15, lk = lane >> 4;
    const float* src;
    if (c < 1024) {
        int n = c >> 8, k = (c >> 6) & 3;
        src = W1 + a * 8192 + (n * 16 + lr) * 128 + k * 32 + lk * 8;
    } else if (c < 2560) {
        int idx = (c - 1024) >> 6;
        int g = idx >> 3, n = (idx >> 1) & 3, kk = idx & 1;
        src = Wih + a * 12288 + (g * 64 + n * 16 + lr) * 64 + kk * 32 + lk * 8;
    } else if (c < 4096) {
        int idx = (c - 2560) >> 6;
        int g = idx >> 3, n = (idx >> 1) & 3, kk = idx & 1;
        src = Whh + a * 12288 + (g * 64 + n * 16 + lr) * 64 + kk * 32 + lk * 8;
    } else {
        int kk = (c - 4096) >> 6;
        src = W2 + a * 1024 + lr * 64 + kk * 32 + lk * 8;
    }
    float4 v0 = ((const float4*)src)[0];
    float4 v1 = ((const float4*)src)[1];
    bf16x8 o = cvt8pair(v0, v1);
    *(bf16x8*)(ws + (size_t)a * 33792 + (size_t)c * 8) = o;
}

// ---------------- main fused kernel ----------------
// grid (B/128, A), 256 threads (4 waves) — the only workgroup size with sane
// codegen (>=512 thr pins VGPR budget to 64 and spills ~350MB; see r4-r6).
// LDS = Whh (24KB, staged once) + 4x2KB transpose = 32KB -> LDS allows 5
// blocks/CU; VGPR=128 caps at 4 blocks/CU = 16 waves/CU = 4 waves/SIMD
// (2x round 3). W1/Wih/W2 fragments stream from packed d_ws (contiguous
// 1KB wave bursts, L1/L2-resident 42KB working set). No barriers after the
// single staging syncthreads. Each wave: 2 row-tiles, 1-ahead x/h prefetch.
extern "C" __global__ void __launch_bounds__(256, 2)
rnn_main(const float* __restrict__ x,     // [B*A, D]
         const float* __restrict__ hin,   // [B, A, H]
         const float* __restrict__ b1, const float* __restrict__ bih,
         const float* __restrict__ bhh, const float* __restrict__ b2,
         const short* __restrict__ wsp,   // packed bf16 weights
         float* __restrict__ qout,        // [B*A, NACT]
         float* __restrict__ hout)        // [B, A, H]
{
    const int a    = blockIdx.y;
    const int bx   = blockIdx.x;
    const int t    = threadIdx.x;
    const int wid  = t >> 6;              // 0..3
    const int lane = t & 63;
    const int lr   = lane & 15;
    const int lk   = lane >> 4;

    __shared__ short whlds[12288];          // 24 KB: Whh fragments (packed chunks 2560..4095)
    __shared__ short zs[4 * 1024];          // 4 per-wave 2KB transpose buffers (8 KB)
    char* zb = (char*)(zs + wid * 1024);

    // ---- stage Whh: 24 rounds x 1KB, split across 4 waves ----
    const short* wsA = wsp + (size_t)a * 33792;
    for (int r = wid; r < 24; r += 4)
        gload_lds16(wsA + 20480 + r * 512 + lane * 8, whlds + r * 512);

    // ---- hoist biases (tile-invariant, per-lane) ----
    float b1v[4], biv[12], bhv[12];
    #pragma unroll
    for (int n = 0; n < 4; ++n) b1v[n] = b1[a * HID + n * 16 + lr];
    #pragma unroll
    for (int g = 0; g < 3; ++g)
        #pragma unroll
        for (int n = 0; n < 4; ++n) {
            biv[g * 4 + n] = bih[a * 3 * HID + g * HID + n * 16 + lr];
            bhv[g * 4 + n] = bhh[a * 3 * HID + g * HID + n * 16 + lr];
        }
    float bqv = b2[a * NACT + lr];

    __syncthreads();   // Whh staged (drains vmcnt)

    const int tile0 = bx * 8 + wid * 2;

    float4 curx[8], curh[4], nxtx[8], nxth[4];

    auto load_tile = [&](int tile, float4* xr, float4* hr) {
        const int arow = tile * 16 + lr;
        const float* xrow = x + ((size_t)arow * NAGENT + a) * DIN + lk * 8;
        const float* hrow = hin + ((size_t)arow * NAGENT + a) * HID + lk * 8;
        #pragma unroll
        for (int k = 0; k < 4; ++k) {
            xr[2 * k]     = *(const float4*)(xrow + k * 32);
            xr[2 * k + 1] = *(const float4*)(xrow + k * 32 + 4);
        }
        #pragma unroll
        for (int kk = 0; kk < 2; ++kk) {
            hr[2 * kk]     = *(const float4*)(hrow + kk * 32);
            hr[2 * kk + 1] = *(const float4*)(hrow + kk * 32 + 4);
        }
    };

    auto compute = [&](int tile, const float4* xr, const float4* hr) {
        // ---- issue late-consumed global loads up front ----
        bf16x8 w2f0 = *(const bf16x8*)(wsA + 32768 + (0 * 64 + lane) * 8);
        bf16x8 w2f1 = *(const bf16x8*)(wsA + 32768 + (1 * 64 + lane) * 8);
        float hp[16];
        #pragma unroll
        for (int n = 0; n < 4; ++n)
            #pragma unroll
            for (int j = 0; j < 4; ++j)
                hp[n * 4 + j] =
                    hin[((size_t)(tile * 16 + lk * 4 + j) * NAGENT + a) * HID + n * 16 + lr];

        bf16x8 xf[4], hf[2];
        #pragma unroll
        for (int k = 0; k < 4; ++k) xf[k] = cvt8pair(xr[2 * k], xr[2 * k + 1]);
        #pragma unroll
        for (int kk = 0; kk < 2; ++kk) hf[kk] = cvt8pair(hr[2 * kk], hr[2 * kk + 1]);

        // ---- fc1: z1 = relu(x @ W1^T + b1), W1 fragments from L1/L2 ----
        f32x4 acc1[4];
        #pragma unroll
        for (int n = 0; n < 4; ++n) acc1[n] = (f32x4){b1v[n], b1v[n], b1v[n], b1v[n]};
        #pragma unroll
        for (int k = 0; k < 4; ++k)
            #pragma unroll
            for (int n = 0; n < 4; ++n) {
                bf16x8 wb = *(const bf16x8*)(wsA + ((n * 4 + k) * 64 + lane) * 8);
                acc1[n] = __builtin_amdgcn_mfma_f32_16x16x32_bf16(xf[k], wb, acc1[n], 0, 0, 0);
            }
        #pragma unroll
        for (int n = 0; n < 4; ++n)
            #pragma unroll
            for (int j = 0; j < 4; ++j) {
                int row = lk * 4 + j, col = n * 16 + lr;
                *(short*)(zb + row * 128 + ((col * 2) ^ ((row & 7) << 4))) =
                    f2bf(fmaxf(acc1[n][j], 0.0f));
            }

        // ---- h-path MFMAs for ALL gates (Whh from LDS; independent of z1,
        //      covers the z1 LDS write->read round trip) ----
        f32x4 aH[12];
        #pragma unroll
        for (int g = 0; g < 3; ++g)
            #pragma unroll
            for (int n = 0; n < 4; ++n) {
                float bh = bhv[g * 4 + n];
                aH[g * 4 + n] = (f32x4){bh, bh, bh, bh};
            }
        #pragma unroll
        for (int kk = 0; kk < 2; ++kk)
            #pragma unroll
            for (int g = 0; g < 3; ++g)
                #pragma unroll
                for (int n = 0; n < 4; ++n) {
                    bf16x8 wh = *(const bf16x8*)(whlds +
                                  (((g * 4 + n) * 2 + kk) * 64 + lane) * 8);
                    aH[g * 4 + n] =
                        __builtin_amdgcn_mfma_f32_16x16x32_bf16(hf[kk], wh, aH[g * 4 + n], 0, 0, 0);
                }

        // ---- z1-path MFMAs (Wih fragments from L1/L2) ----
        bf16x8 za0 = *(const bf16x8*)(zb + lr * 128 + ((0 * 64 + lk * 16) ^ ((lr & 7) << 4)));
        bf16x8 za1 = *(const bf16x8*)(zb + lr * 128 + ((1 * 64 + lk * 16) ^ ((lr & 7) << 4)));

        float rg[16], zg[16];
        #pragma unroll
        for (int g = 0; g < 3; ++g) {
            f32x4 aI[4];
            #pragma unroll
            for (int n = 0; n < 4; ++n) {
                float bi = biv[g * 4 + n];
                aI[n] = (f32x4){bi, bi, bi, bi};
            }
            #pragma unroll
            for (int n = 0; n < 4; ++n) {
                bf16x8 wi0 = *(const bf16x8*)(wsA + 8192 +
                              (((g * 4 + n) * 2 + 0) * 64 + lane) * 8);
                bf16x8 wi1 = *(const bf16x8*)(wsA + 8192 +
                              (((g * 4 + n) * 2 + 1) * 64 + lane) * 8);
                aI[n] = __builtin_amdgcn_mfma_f32_16x16x32_bf16(za0, wi0, aI[n], 0, 0, 0);
                aI[n] = __builtin_amdgcn_mfma_f32_16x16x32_bf16(za1, wi1, aI[n], 0, 0, 0);
            }
            if (g == 0) {
                #pragma unroll
                for (int n = 0; n < 4; ++n)
                    #pragma unroll
                    for (int j = 0; j < 4; ++j)
                        rg[n * 4 + j] = sigmoid_f(aI[n][j] + aH[n][j]);
            } else if (g == 1) {
                #pragma unroll
                for (int n = 0; n < 4; ++n)
                    #pragma unroll
                    for (int j = 0; j < 4; ++j)
                        zg[n * 4 + j] = sigmoid_f(aI[n][j] + aH[4 + n][j]);
            } else {
                #pragma unroll
                for (int n = 0; n < 4; ++n)
                    #pragma unroll
                    for (int j = 0; j < 4; ++j) {
                        int row = lk * 4 + j, col = n * 16 + lr;
                        float nn = tanh_f(aI[n][j] + rg[n * 4 + j] * aH[8 + n][j]);
                        float zv = zg[n * 4 + j];
                        float hv = (1.0f - zv) * nn + zv * hp[n * 4 + j];
                        hout[((size_t)(tile * 16 + row) * NAGENT + a) * HID + col] = hv;
                        *(short*)(zb + row * 128 + ((col * 2) ^ ((row & 7) << 4))) = f2bf(hv);
                    }
            }
        }

        // ---- fc2: q = h_new @ W2^T + b2 ----
        f32x4 q = (f32x4){bqv, bqv, bqv, bqv};
        bf16x8 ha0 = *(const bf16x8*)(zb + lr * 128 + ((0 * 64 + lk * 16) ^ ((lr & 7) << 4)));
        bf16x8 ha1 = *(const bf16x8*)(zb + lr * 128 + ((1 * 64 + lk * 16) ^ ((lr & 7) << 4)));
        q = __builtin_amdgcn_mfma_f32_16x16x32_bf16(ha0, w2f0, q, 0, 0, 0);
        q = __builtin_amdgcn_mfma_f32_16x16x32_bf16(ha1, w2f1, q, 0, 0, 0);
        #pragma unroll
        for (int j = 0; j < 4; ++j)
            qout[((size_t)(tile * 16 + lk * 4 + j) * NAGENT + a) * NACT + lr] = q[j];
    };

    // ---- pipelined tile loop: prefetch next tile during compute ----
    load_tile(tile0, curx, curh);
    #pragma unroll
    for (int i = 0; i < 2; ++i) {
        if (i < 1) load_tile(tile0 + i + 1, nxtx, nxth);
        compute(tile0 + i, curx, curh);
        if (i < 1) {
            #pragma unroll
            for (int u = 0; u < 8; ++u) curx[u] = nxtx[u];
            #pragma unroll
            for (int u = 0; u < 4; ++u) curh[u] = nxth[u];
        }
    }
}

extern "C" void kernel_launch(void* const* d_in, const int* in_sizes, int n_in,
                              void* d_out, int out_size, void* d_ws, size_t ws_size,
                              hipStream_t stream)
{
    const float* x   = (const float*)d_in[0];
    const float* hin = (const float*)d_in[1];
    const float* W1  = (const float*)d_in[2];
    const float* b1  = (const float*)d_in[3];
    const float* Wih = (const float*)d_in[4];
    const float* bih = (const float*)d_in[5];
    const float* Whh = (const float*)d_in[6];
    const float* bhh = (const float*)d_in[7];
    const float* W2  = (const float*)d_in[8];
    const float* b2  = (const float*)d_in[9];

    const int B = in_sizes[0] / (NAGENT * DIN);   // 16384

    float* qout = (float*)d_out;                              // [B*A, NACT]
    float* hout = (float*)d_out + (size_t)B * NAGENT * NACT;  // [B, A, H]

    short* wsp = (short*)d_ws;                                // 540,672 B packed

    conv_weights_packed<<<dim3(17, NAGENT), 256, 0, stream>>>(W1, Wih, Whh, W2, wsp);

    dim3 grid(B / 128, NAGENT);
    rnn_main<<<grid, 256, 0, stream>>>(x, hin, b1, bih, bhh, b2, wsp, qout, hout);
}